// Round 10
// baseline (192.893 us; speedup 1.0000x reference)
//
#include <hip/hip_runtime.h>

#define BT 16384
#define DK 4096
#define NE 64
#define BM 32                 // rows per block
#define NW 8                  // waves per block = split-K factor
#define KW (DK / NW)          // 512 k per wave
#define KC 32                 // k floats per step
#define NS (KW / KC)          // 16 steps
#define NPROBS (BT * NE)
#define NIDX (NPROBS)
#define NWTS (NPROBS + BT * 2)

#define COMP(v, m) ((m) == 0 ? (v).x : (m) == 1 ? (v).y : (m) == 2 ? (v).z : (v).w)

// ---- pre-kernel: W (64 x 4096) -> W_T (4096 x 64, k-major) ----
__global__ __launch_bounds__(256) void wt_transpose(
    const float* __restrict__ W, float* __restrict__ WT)
{
    const int idx = blockIdx.x * 1024 + threadIdx.x * 4;
    const int k = idx >> 6;
    const int e = idx & 63;
    float4 v;
    v.x = W[(long)(e + 0) * DK + k];
    v.y = W[(long)(e + 1) * DK + k];
    v.z = W[(long)(e + 2) * DK + k];
    v.w = W[(long)(e + 3) * DK + k];
    *reinterpret_cast<float4*>(WT + idx) = v;
}

// Wave wv owns k-slice [wv*512, +512) of all 32 rows x 64 experts.
// lane = rlg*8+elg: tile 4 rows (ii*8+rlg) x 8 experts (elg*8+j); acc[4][8].
// X: wave-private LDS [buf 256 f4][8 t][32 rows]; conflict-free (R9: 0).
// W: dense VMEM from W_T (L1/L2-resident).
// VMCNT QUEUE DISCIPLINE (the R10 fix): per step, the ONLY wait that can see
// the X HBM loads is the top-of-step ds_write (issued a full step earlier ->
// free); fresh X loads are issued right after, pinned by sched_barrier, and
// get drained exactly once at the first W-wait instead of poisoning all of
// them (R9: every W-wait drained in-flight HBM X -> 84% stall).
__global__ __launch_bounds__(512) void token_router(
    const float* __restrict__ x, const float* __restrict__ WT,
    float* __restrict__ out)
{
    __shared__ float4 sh4[NW * 512];   // 64 KB: per wave [2 buf][8 t][32 rows]

    const int tid  = threadIdx.x;
    const int wv   = tid >> 6;
    const int lane = tid & 63;
    const int rlg  = lane >> 3;
    const int elg  = lane & 7;
    const long rowbase = (long)blockIdx.x * BM;
    const int kq0 = wv * KW;

    // lane's X stream: row = lane&31, base k-f4 = lane>>5 (t parity)
    const int srow = lane & 31;
    const float4* gxc = reinterpret_cast<const float4*>(
        x + (rowbase + srow) * (long)DK + kq0 + (lane >> 5) * 4);

    float4* const reg = sh4 + wv * 512;            // wave-private region
    const float4* wtc = reinterpret_cast<const float4*>(
        WT + (long)kq0 * 64 + elg * 8);            // dense W_T base (f4 units)

    float acc[4][8];
#pragma unroll
    for (int ii = 0; ii < 4; ++ii)
#pragma unroll
        for (int j = 0; j < 8; ++j) acc[ii][j] = 0.f;

    // prologue: chunk 0 -> buf0 (slots l,64+l,128+l,192+l = t {0,2,4,6}+(l>>5))
    {
        float4 a0 = gxc[0], a1 = gxc[2], a2 = gxc[4], a3 = gxc[6];
        reg[lane]       = a0;
        reg[64 + lane]  = a1;
        reg[128 + lane] = a2;
        reg[192 + lane] = a3;
    }
    // px holds chunk 1
    float4 px0 = gxc[8], px1 = gxc[10], px2 = gxc[12], px3 = gxc[14];
    gxc += 8;   // now at chunk-1 base; refill reads gxc[8..14] = chunk c+2

    for (int c = 0; c < NS; ++c) {
        const int buf = (c & 1) * 256;
        const int nb  = buf ^ 256;
        // (A) write chunk c+1 (loaded a full step ago -> vmcnt wait ~free;
        //     queue contains ONLY these X loads here)
        if (c + 1 < NS) {
            reg[nb + lane]       = px0;
            reg[nb + 64 + lane]  = px1;
            reg[nb + 128 + lane] = px2;
            reg[nb + 192 + lane] = px3;
        }
        __builtin_amdgcn_sched_barrier(0);
        // (B) issue chunk c+2 X loads; pinned here so they sit at the FRONT
        //     of the queue and are drained once, early, not at every W-wait.
        if (c + 2 < NS) {
            px0 = gxc[8]; px1 = gxc[10]; px2 = gxc[12]; px3 = gxc[14];
        }
        __builtin_amdgcn_sched_barrier(0);
        // (C) compute: per t, W loads then FMAs; after the first W-wait the
        //     queue is pure W (L1/L2-fast).
#pragma unroll
        for (int t = 0; t < 8; ++t) {
            float4 xq[4];
#pragma unroll
            for (int ii = 0; ii < 4; ++ii)
                xq[ii] = reg[buf + t * 32 + ii * 8 + rlg];
            float4 wq[4][2];
#pragma unroll
            for (int kk = 0; kk < 4; ++kk)
#pragma unroll
                for (int h = 0; h < 2; ++h)
                    wq[kk][h] = wtc[(t * 4 + kk) * 16 + h];
#pragma unroll
            for (int ii = 0; ii < 4; ++ii)
#pragma unroll
                for (int j = 0; j < 8; ++j) {
                    acc[ii][j] = fmaf(xq[ii].x, COMP(wq[0][j >> 2], j & 3), acc[ii][j]);
                    acc[ii][j] = fmaf(xq[ii].y, COMP(wq[1][j >> 2], j & 3), acc[ii][j]);
                    acc[ii][j] = fmaf(xq[ii].z, COMP(wq[2][j >> 2], j & 3), acc[ii][j]);
                    acc[ii][j] = fmaf(xq[ii].w, COMP(wq[3][j >> 2], j & 3), acc[ii][j]);
                }
        }
        wtc += 512;   // 32 k rows x 16 f4
        gxc += 8;     // 32 k floats
    }

    // ---- split-K tree reduction (fixed order -> deterministic fp32) ----
    auto dump = [&](float4* r) {
#pragma unroll
        for (int ii = 0; ii < 4; ++ii) {
            r[(ii * 2 + 0) * 64 + lane] = make_float4(acc[ii][0], acc[ii][1], acc[ii][2], acc[ii][3]);
            r[(ii * 2 + 1) * 64 + lane] = make_float4(acc[ii][4], acc[ii][5], acc[ii][6], acc[ii][7]);
        }
    };
    auto addin = [&](const float4* r) {
#pragma unroll
        for (int ii = 0; ii < 4; ++ii) {
            float4 a = r[(ii * 2 + 0) * 64 + lane];
            float4 b = r[(ii * 2 + 1) * 64 + lane];
            acc[ii][0] += a.x; acc[ii][1] += a.y; acc[ii][2] += a.z; acc[ii][3] += a.w;
            acc[ii][4] += b.x; acc[ii][5] += b.y; acc[ii][6] += b.z; acc[ii][7] += b.w;
        }
    };
    __syncthreads();
    if (wv >= 4) dump(sh4 + (wv - 4) * 512);
    __syncthreads();
    if (wv < 4) addin(sh4 + wv * 512);
    __syncthreads();
    if (wv == 2 || wv == 3) dump(sh4 + (wv - 2) * 512);
    __syncthreads();
    if (wv < 2) addin(sh4 + wv * 512);
    __syncthreads();
    if (wv == 1) dump(sh4);
    __syncthreads();

    if (wv == 0) {
        addin(sh4);
#pragma unroll
        for (int ii = 0; ii < 4; ++ii) {
            float l[8];
#pragma unroll
            for (int j = 0; j < 8; ++j) l[j] = acc[ii][j];
            float m = l[0];
#pragma unroll
            for (int j = 1; j < 8; ++j) m = fmaxf(m, l[j]);
            m = fmaxf(m, __shfl_xor(m, 1));
            m = fmaxf(m, __shfl_xor(m, 2));
            m = fmaxf(m, __shfl_xor(m, 4));
            float s = 0.f;
#pragma unroll
            for (int j = 0; j < 8; ++j) s += __expf(l[j] - m);
            s += __shfl_xor(s, 1);
            s += __shfl_xor(s, 2);
            s += __shfl_xor(s, 4);
            const float inv = 1.f / s;
            float p[8];
#pragma unroll
            for (int j = 0; j < 8; ++j) p[j] = __expf(l[j] - m) * inv;

            float v1 = p[0], v2 = -1.f;
            int   i1 = elg * 8, i2 = elg * 8;
#pragma unroll
            for (int j = 1; j < 8; ++j) {
                const int idx = elg * 8 + j;
                if (p[j] > v1)      { v2 = v1; i2 = i1; v1 = p[j]; i1 = idx; }
                else if (p[j] > v2) { v2 = p[j]; i2 = idx; }
            }
#pragma unroll
            for (int ms = 1; ms < 8; ms <<= 1) {
                float b1 = __shfl_xor(v1, ms);
                float b2 = __shfl_xor(v2, ms);
                int  bi1 = __shfl_xor(i1, ms);
                int  bi2 = __shfl_xor(i2, ms);
                float n1, n2; int ni1, ni2;
                const bool btop = (b1 > v1) || (b1 == v1 && bi1 < i1);
                if (btop) {
                    n1 = b1; ni1 = bi1;
                    const bool asec = (v1 > b2) || (v1 == b2 && i1 < bi2);
                    n2 = asec ? v1 : b2; ni2 = asec ? i1 : bi2;
                } else {
                    n1 = v1; ni1 = i1;
                    const bool bsec = (b1 > v2) || (b1 == v2 && bi1 < i2);
                    n2 = bsec ? b1 : v2; ni2 = bsec ? bi1 : i2;
                }
                v1 = n1; i1 = ni1; v2 = n2; i2 = ni2;
            }

            const long grow = rowbase + ii * 8 + rlg;
            *reinterpret_cast<float4*>(&out[grow * (long)NE + elg * 8]) =
                make_float4(p[0], p[1], p[2], p[3]);
            *reinterpret_cast<float4*>(&out[grow * (long)NE + elg * 8 + 4]) =
                make_float4(p[4], p[5], p[6], p[7]);
            if (elg == 0) {
                out[NIDX + grow * 2 + 0] = (float)i1;
                out[NIDX + grow * 2 + 1] = (float)i2;
                const float dn = v1 + v2 + 1e-9f;
                out[NWTS + grow * 2 + 0] = v1 / dn;
                out[NWTS + grow * 2 + 1] = v2 / dn;
            }
        }
    }
}

extern "C" void kernel_launch(void* const* d_in, const int* in_sizes, int n_in,
                              void* d_out, int out_size, void* d_ws, size_t ws_size,
                              hipStream_t stream) {
    const float* x = (const float*)d_in[0];
    const float* W = (const float*)d_in[1];
    float* out = (float*)d_out;
    float* WT  = (float*)d_ws;   // 4096*64*4 = 1 MB scratch

    wt_transpose<<<dim3(256), dim3(256), 0, stream>>>(W, WT);
    token_router<<<dim3(BT / BM), dim3(512), 0, stream>>>(x, WT, out);
}

// Round 11
// 119.922 us; speedup vs baseline: 1.6085x; 1.6085x over previous
//
#include <hip/hip_runtime.h>

#define BT 16384
#define DK 4096
#define NE 64
#define BM 64
#define NSTEP 128             // K steps of 32
#define NPROBS (BT * NE)
#define NIDX (NPROBS)
#define NWTS (NPROBS + BT * 2)

typedef __bf16 bf16x8 __attribute__((ext_vector_type(8)));
typedef float f32x4 __attribute__((ext_vector_type(4)));

__device__ __forceinline__ unsigned asu(float f) { return __builtin_bit_cast(unsigned, f); }
__device__ __forceinline__ float asf(unsigned u) { return __builtin_bit_cast(float, u); }

// Split 8 f32 into 3 bf16 planes (truncation split; residuals exact in f32).
// Plane words pack (elem 2d) in low 16, (elem 2d+1) in high 16.
__device__ __forceinline__ void split3(const float* xx, uint4* pl) {
    unsigned h0[8], h1[8], h2[8];
#pragma unroll
    for (int j = 0; j < 8; ++j) {
        const float xf = xx[j];
        const unsigned a0 = asu(xf) & 0xFFFF0000u;
        const float r1 = xf - asf(a0);
        const unsigned a1 = asu(r1) & 0xFFFF0000u;
        const float r2 = r1 - asf(a1);
        const unsigned a2 = asu(r2) & 0xFFFF0000u;
        h0[j] = a0; h1[j] = a1; h2[j] = a2;
    }
    pl[0] = make_uint4((h0[0] >> 16) | (h0[1] & 0xFFFF0000u), (h0[2] >> 16) | (h0[3] & 0xFFFF0000u),
                       (h0[4] >> 16) | (h0[5] & 0xFFFF0000u), (h0[6] >> 16) | (h0[7] & 0xFFFF0000u));
    pl[1] = make_uint4((h1[0] >> 16) | (h1[1] & 0xFFFF0000u), (h1[2] >> 16) | (h1[3] & 0xFFFF0000u),
                       (h1[4] >> 16) | (h1[5] & 0xFFFF0000u), (h1[6] >> 16) | (h1[7] & 0xFFFF0000u));
    pl[2] = make_uint4((h2[0] >> 16) | (h2[1] & 0xFFFF0000u), (h2[2] >> 16) | (h2[3] & 0xFFFF0000u),
                       (h2[4] >> 16) | (h2[5] & 0xFFFF0000u), (h2[6] >> 16) | (h2[7] & 0xFFFF0000u));
}

// ---- prep: W (64 x 4096 row-major f32) -> 3 bf16 planes in B-FRAGMENT order.
// WF u4-entry ((ks*4 + et)*3 + p)*64 + l  holds, for lane l: 8 bf16 of plane p,
// expert e = et*16 + (l&15), k = ks*32 + (l>>4)*8 + j (j=0..7).
__global__ __launch_bounds__(256) void w_prep(
    const float* __restrict__ W, uint4* __restrict__ WF)
{
    const int g  = blockIdx.x * 256 + threadIdx.x;   // 32768 threads
    const int e  = g >> 9;
    const int kg = g & 511;
    const float4 v0 = *(const float4*)(W + (long)e * DK + kg * 8);
    const float4 v1 = *(const float4*)(W + (long)e * DK + kg * 8 + 4);
    float xx[8] = {v0.x, v0.y, v0.z, v0.w, v1.x, v1.y, v1.z, v1.w};
    uint4 pl[3];
    split3(xx, pl);
    const int ks = kg >> 2;
    const int l  = (e & 15) | ((kg & 3) << 4);
    const int et = e >> 4;
#pragma unroll
    for (int p = 0; p < 3; ++p)
        WF[((ks * 4 + et) * 3 + p) * 64 + l] = pl[p];
}

// Main: 256 blocks x 64 rows, 8 waves = (row-tile rt 0..3) x (expert-half eh).
// Per wave per 32-k step: stage own A (16 rows) f32->3 bf16 planes into
// wave-private LDS; 6 lane-linear B-frag VMEM loads; 12 MFMA (6 split terms
// x 2 e-tiles). No barriers in the main loop. vmcnt queue: B issued before
// the X prefetch so the compiler's counted wait leaves X outstanding.
__global__ __launch_bounds__(512) void token_router(
    const float* __restrict__ x, const uint4* __restrict__ WF,
    float* __restrict__ out)
{
    __shared__ uint4 ash[8 * 2 * 3 * 64];   // 48 KB: [wave][buf][plane][64 slots]
    __shared__ float lg[BM * 68];
    __shared__ float rowm[BM], rowinv[BM];

    const int tid  = threadIdx.x;
    const int wv   = tid >> 6;
    const int lane = tid & 63;
    const int rt   = wv >> 1;
    const int eh   = wv & 1;
    const long rowbase = (long)blockIdx.x * BM;

    // X source: lane covers row rt*16 + (lane>>2), k-octet lane&3 of each step
    const float4* gx4 = (const float4*)(
        x + (rowbase + rt * 16 + (lane >> 2)) * (long)DK + (lane & 3) * 8);
    const uint4* wfl = WF + lane;

    // swizzled LDS slots (bank-balanced; see analysis): phys = s ^ (r&3)
    const int wslot = (lane >> 2) * 4 + ((lane & 3) ^ ((lane >> 2) & 3));
    const int rslot = (lane & 15) * 4 + (((lane >> 4) ^ lane) & 3);

    f32x4 acc0 = {0.f, 0.f, 0.f, 0.f};
    f32x4 acc1 = {0.f, 0.f, 0.f, 0.f};

    // prologue: step 0 -> buf0; X(1),X(2) into parity hold sets
    {
        const float4 t0 = gx4[0], t1 = gx4[1];
        float xx[8] = {t0.x, t0.y, t0.z, t0.w, t1.x, t1.y, t1.z, t1.w};
        uint4 pl[3];
        split3(xx, pl);
#pragma unroll
        for (int p = 0; p < 3; ++p) ash[(wv * 6 + p) * 64 + wslot] = pl[p];
    }
    float4 pa0 = gx4[8],  pa1 = gx4[9];     // X(1)
    float4 pb0 = gx4[16], pb1 = gx4[17];    // X(2)

#define STEPBODY(C, P0, P1) do {                                              \
    const int cur_ = (C) & 1, nb_ = cur_ ^ 1;                                 \
    if ((C) + 1 < NSTEP) {                                                    \
        float xx[8] = {P0.x, P0.y, P0.z, P0.w, P1.x, P1.y, P1.z, P1.w};       \
        uint4 pl[3];                                                          \
        split3(xx, pl);                                                       \
        _Pragma("unroll")                                                     \
        for (int p = 0; p < 3; ++p)                                           \
            ash[((wv * 2 + nb_) * 3 + p) * 64 + wslot] = pl[p];               \
    }                                                                         \
    __builtin_amdgcn_sched_barrier(0);                                        \
    uint4 bf[2][3];                                                           \
    _Pragma("unroll")                                                         \
    for (int t = 0; t < 2; ++t)                                               \
        _Pragma("unroll")                                                     \
        for (int p = 0; p < 3; ++p)                                           \
            bf[t][p] = wfl[(((C) * 4 + 2 * eh + t) * 3 + p) * 64];            \
    __builtin_amdgcn_sched_barrier(0);                                        \
    if ((C) + 3 < NSTEP) {                                                    \
        P0 = gx4[((C) + 3) * 8];                                              \
        P1 = gx4[((C) + 3) * 8 + 1];                                          \
    }                                                                         \
    __builtin_amdgcn_sched_barrier(0);                                        \
    uint4 af[3];                                                              \
    _Pragma("unroll")                                                         \
    for (int p = 0; p < 3; ++p)                                               \
        af[p] = ash[((wv * 2 + cur_) * 3 + p) * 64 + rslot];                  \
    const bf16x8 a0 = __builtin_bit_cast(bf16x8, af[0]);                      \
    const bf16x8 a1 = __builtin_bit_cast(bf16x8, af[1]);                      \
    const bf16x8 a2 = __builtin_bit_cast(bf16x8, af[2]);                      \
    _Pragma("unroll")                                                         \
    for (int t = 0; t < 2; ++t) {                                             \
        const bf16x8 b0 = __builtin_bit_cast(bf16x8, bf[t][0]);               \
        const bf16x8 b1 = __builtin_bit_cast(bf16x8, bf[t][1]);               \
        const bf16x8 b2 = __builtin_bit_cast(bf16x8, bf[t][2]);               \
        f32x4& A = t ? acc1 : acc0;                                           \
        A = __builtin_amdgcn_mfma_f32_16x16x32_bf16(a0, b0, A, 0, 0, 0);      \
        A = __builtin_amdgcn_mfma_f32_16x16x32_bf16(a0, b1, A, 0, 0, 0);      \
        A = __builtin_amdgcn_mfma_f32_16x16x32_bf16(a1, b0, A, 0, 0, 0);      \
        A = __builtin_amdgcn_mfma_f32_16x16x32_bf16(a1, b1, A, 0, 0, 0);      \
        A = __builtin_amdgcn_mfma_f32_16x16x32_bf16(a0, b2, A, 0, 0, 0);      \
        A = __builtin_amdgcn_mfma_f32_16x16x32_bf16(a2, b0, A, 0, 0, 0);      \
    }                                                                         \
} while (0)

    for (int c = 0; c < NSTEP; c += 2) {
        STEPBODY(c, pa0, pa1);
        STEPBODY(c + 1, pb0, pb1);
    }
#undef STEPBODY

    // ---- logits to LDS (C/D layout: col = lane&15, row = (lane>>4)*4 + jj) ----
#pragma unroll
    for (int jj = 0; jj < 4; ++jj) {
        const int row = rt * 16 + (lane >> 4) * 4 + jj;
        lg[row * 68 + (2 * eh + 0) * 16 + (lane & 15)] = acc0[jj];
        lg[row * 68 + (2 * eh + 1) * 16 + (lane & 15)] = acc1[jj];
    }
    __syncthreads();

    // ---- per-row softmax stats + stable top-2 (one thread per row) ----
    if (tid < BM) {
        const int row = tid;
        float m = -3.4e38f;
        for (int e = 0; e < NE; ++e) m = fmaxf(m, lg[row * 68 + e]);
        float s = 0.f;
        float v1 = -1.f, v2 = -1.f;
        int   i1 = 0,    i2 = 0;
        for (int e = 0; e < NE; ++e) {
            const float p = __expf(lg[row * 68 + e] - m);
            s += p;
            if (p > v1)      { v2 = v1; i2 = i1; v1 = p; i1 = e; }
            else if (p > v2) { v2 = p; i2 = e; }
        }
        const float inv = 1.f / s;
        rowm[row]   = m;
        rowinv[row] = inv;
        const long grow = rowbase + row;
        const float p1 = v1 * inv, p2 = v2 * inv;
        const float dn = p1 + p2 + 1e-9f;
        out[NIDX + grow * 2 + 0] = (float)i1;
        out[NIDX + grow * 2 + 1] = (float)i2;
        out[NWTS + grow * 2 + 0] = p1 / dn;
        out[NWTS + grow * 2 + 1] = p2 / dn;
    }
    __syncthreads();

    // ---- probs write: 512 threads x 8 floats, coalesced ----
    {
        const int row = tid >> 3;
        const int e0  = (tid & 7) << 3;
        const float m = rowm[row], inv = rowinv[row];
        const long grow = rowbase + row;
        const float4 l4a = *reinterpret_cast<const float4*>(&lg[row * 68 + e0]);
        const float4 l4b = *reinterpret_cast<const float4*>(&lg[row * 68 + e0 + 4]);
        float4 p0, p1;
        p0.x = __expf(l4a.x - m) * inv;
        p0.y = __expf(l4a.y - m) * inv;
        p0.z = __expf(l4a.z - m) * inv;
        p0.w = __expf(l4a.w - m) * inv;
        p1.x = __expf(l4b.x - m) * inv;
        p1.y = __expf(l4b.y - m) * inv;
        p1.z = __expf(l4b.z - m) * inv;
        p1.w = __expf(l4b.w - m) * inv;
        *reinterpret_cast<float4*>(&out[grow * (long)NE + e0])     = p0;
        *reinterpret_cast<float4*>(&out[grow * (long)NE + e0 + 4]) = p1;
    }
}

extern "C" void kernel_launch(void* const* d_in, const int* in_sizes, int n_in,
                              void* d_out, int out_size, void* d_ws, size_t ws_size,
                              hipStream_t stream) {
    const float* x = (const float*)d_in[0];
    const float* W = (const float*)d_in[1];
    float* out = (float*)d_out;
    uint4* WF  = (uint4*)d_ws;   // 1.5 MB fragment-ordered W planes

    w_prep<<<dim3(128), dim3(256), 0, stream>>>(W, WF);
    token_router<<<dim3(BT / BM), dim3(512), 0, stream>>>(x, WF, out);
}

// Round 12
// 114.441 us; speedup vs baseline: 1.6855x; 1.0479x over previous
//
#include <hip/hip_runtime.h>

#define BT 16384
#define DK 4096
#define NE 64
#define BM 32                 // rows per block -> grid 512 = 2 blocks/CU
#define NSQ 32                // steps per wave (K quarter 1024 / 32)
#define NPROBS (BT * NE)
#define NIDX (NPROBS)
#define NWTS (NPROBS + BT * 2)

typedef __bf16 bf16x8 __attribute__((ext_vector_type(8)));
typedef float f32x4 __attribute__((ext_vector_type(4)));

__device__ __forceinline__ unsigned asu(float f) { return __builtin_bit_cast(unsigned, f); }
__device__ __forceinline__ float asf(unsigned u) { return __builtin_bit_cast(float, u); }

// Split 8 f32 into 3 bf16 planes (truncation split; residuals exact in f32).
__device__ __forceinline__ void split3(const float* xx, uint4* pl) {
    unsigned h0[8], h1[8], h2[8];
#pragma unroll
    for (int j = 0; j < 8; ++j) {
        const float xf = xx[j];
        const unsigned a0 = asu(xf) & 0xFFFF0000u;
        const float r1 = xf - asf(a0);
        const unsigned a1 = asu(r1) & 0xFFFF0000u;
        const float r2 = r1 - asf(a1);
        const unsigned a2 = asu(r2) & 0xFFFF0000u;
        h0[j] = a0; h1[j] = a1; h2[j] = a2;
    }
    pl[0] = make_uint4((h0[0] >> 16) | (h0[1] & 0xFFFF0000u), (h0[2] >> 16) | (h0[3] & 0xFFFF0000u),
                       (h0[4] >> 16) | (h0[5] & 0xFFFF0000u), (h0[6] >> 16) | (h0[7] & 0xFFFF0000u));
    pl[1] = make_uint4((h1[0] >> 16) | (h1[1] & 0xFFFF0000u), (h1[2] >> 16) | (h1[3] & 0xFFFF0000u),
                       (h1[4] >> 16) | (h1[5] & 0xFFFF0000u), (h1[6] >> 16) | (h1[7] & 0xFFFF0000u));
    pl[2] = make_uint4((h2[0] >> 16) | (h2[1] & 0xFFFF0000u), (h2[2] >> 16) | (h2[3] & 0xFFFF0000u),
                       (h2[4] >> 16) | (h2[5] & 0xFFFF0000u), (h2[6] >> 16) | (h2[7] & 0xFFFF0000u));
}

// prep: W (64 x 4096 f32) -> 3 bf16 planes in B-fragment order (as R11, validated).
// WF entry ((ks*4 + et)*3 + p)*64 + l : lane l, expert et*16+(l&15), k = ks*32+(l>>4)*8+j
__global__ __launch_bounds__(256) void w_prep(
    const float* __restrict__ W, uint4* __restrict__ WF)
{
    const int g  = blockIdx.x * 256 + threadIdx.x;
    const int e  = g >> 9;
    const int kg = g & 511;
    const float4 v0 = *(const float4*)(W + (long)e * DK + kg * 8);
    const float4 v1 = *(const float4*)(W + (long)e * DK + kg * 8 + 4);
    float xx[8] = {v0.x, v0.y, v0.z, v0.w, v1.x, v1.y, v1.z, v1.w};
    uint4 pl[3];
    split3(xx, pl);
    const int ks = kg >> 2;
    const int l  = (e & 15) | ((kg & 3) << 4);
    const int et = e >> 4;
#pragma unroll
    for (int p = 0; p < 3; ++p)
        WF[((ks * 4 + et) * 3 + p) * 64 + l] = pl[p];
}

// Main: 512 blocks x 32 rows, 8 waves = (eh expert-half) x (kh K-quarter).
// Wave: 2 row-tiles (rt 0,1) x 2 expert-tiles x its 1024-k slice, 32 steps.
// A loaded DIRECTLY in fragment layout (row = lane&15, k-octet = lane>>4):
// no LDS in the main loop. B from frag-ordered WF, coalesced. Queue order per
// step: B first, split3 covers B latency, X(c+2) after B (B-wait=vmcnt(4)
// never drains X). Split-K combined by 4-phase deterministic add into lg.
__global__ __launch_bounds__(512) void token_router(
    const float* __restrict__ x, const uint4* __restrict__ WF,
    float* __restrict__ out)
{
    __shared__ float lg[BM * 68 + 2 * BM];   // 9 KB: logits + rowm/rowinv

    const int tid  = threadIdx.x;
    const int wv   = tid >> 6;
    const int lane = tid & 63;
    const int eh   = wv & 1;          // expert half
    const int kh   = wv >> 1;         // K quarter 0..3
    const long rowbase = (long)blockIdx.x * BM;

    // A sources in fragment layout
    const float* gxr0 = x + (rowbase + (lane & 15)) * (long)DK + kh * 1024 + ((lane >> 4) << 3);
    const float* gxr1 = gxr0 + 16 * (long)DK;
    const uint4* wfl = WF + ((long)(kh * 32) * 12 + (2 * eh) * 3) * 64 + lane;

    f32x4 acc00 = {0.f,0.f,0.f,0.f}, acc01 = {0.f,0.f,0.f,0.f};
    f32x4 acc10 = {0.f,0.f,0.f,0.f}, acc11 = {0.f,0.f,0.f,0.f};

    // X prefetch: parity sets hold steps c (pa) and c+1 (pb)
    float4 pa00 = *(const float4*)(gxr0);
    float4 pa01 = *(const float4*)(gxr0 + 4);
    float4 pa10 = *(const float4*)(gxr1);
    float4 pa11 = *(const float4*)(gxr1 + 4);
    float4 pb00 = *(const float4*)(gxr0 + 32);
    float4 pb01 = *(const float4*)(gxr0 + 36);
    float4 pb10 = *(const float4*)(gxr1 + 32);
    float4 pb11 = *(const float4*)(gxr1 + 36);

#define STEPBODY(C, P00, P01, P10, P11) do {                                  \
    uint4 bfr[2][3];                                                          \
    _Pragma("unroll")                                                         \
    for (int t = 0; t < 2; ++t)                                               \
        _Pragma("unroll")                                                     \
        for (int p = 0; p < 3; ++p)                                           \
            bfr[t][p] = wfl[((C) * 12 + t * 3 + p) * 64];                     \
    __builtin_amdgcn_sched_barrier(0);                                        \
    float xx0[8] = {P00.x, P00.y, P00.z, P00.w, P01.x, P01.y, P01.z, P01.w};  \
    float xx1[8] = {P10.x, P10.y, P10.z, P10.w, P11.x, P11.y, P11.z, P11.w};  \
    uint4 pl0[3], pl1[3];                                                     \
    split3(xx0, pl0);                                                         \
    split3(xx1, pl1);                                                         \
    __builtin_amdgcn_sched_barrier(0);                                        \
    if ((C) + 2 < NSQ) {                                                      \
        P00 = *(const float4*)(gxr0 + ((C) + 2) * 32);                        \
        P01 = *(const float4*)(gxr0 + ((C) + 2) * 32 + 4);                    \
        P10 = *(const float4*)(gxr1 + ((C) + 2) * 32);                        \
        P11 = *(const float4*)(gxr1 + ((C) + 2) * 32 + 4);                    \
    }                                                                         \
    __builtin_amdgcn_sched_barrier(0);                                        \
    const bf16x8 A00 = __builtin_bit_cast(bf16x8, pl0[0]);                    \
    const bf16x8 A01 = __builtin_bit_cast(bf16x8, pl0[1]);                    \
    const bf16x8 A02 = __builtin_bit_cast(bf16x8, pl0[2]);                    \
    const bf16x8 A10 = __builtin_bit_cast(bf16x8, pl1[0]);                    \
    const bf16x8 A11 = __builtin_bit_cast(bf16x8, pl1[1]);                    \
    const bf16x8 A12 = __builtin_bit_cast(bf16x8, pl1[2]);                    \
    _Pragma("unroll")                                                         \
    for (int t = 0; t < 2; ++t) {                                             \
        const bf16x8 B0 = __builtin_bit_cast(bf16x8, bfr[t][0]);              \
        const bf16x8 B1 = __builtin_bit_cast(bf16x8, bfr[t][1]);              \
        const bf16x8 B2 = __builtin_bit_cast(bf16x8, bfr[t][2]);              \
        f32x4& C0 = t ? acc01 : acc00;                                        \
        f32x4& C1 = t ? acc11 : acc10;                                        \
        C0 = __builtin_amdgcn_mfma_f32_16x16x32_bf16(A00, B0, C0, 0, 0, 0);   \
        C0 = __builtin_amdgcn_mfma_f32_16x16x32_bf16(A00, B1, C0, 0, 0, 0);   \
        C0 = __builtin_amdgcn_mfma_f32_16x16x32_bf16(A01, B0, C0, 0, 0, 0);   \
        C0 = __builtin_amdgcn_mfma_f32_16x16x32_bf16(A01, B1, C0, 0, 0, 0);   \
        C0 = __builtin_amdgcn_mfma_f32_16x16x32_bf16(A00, B2, C0, 0, 0, 0);   \
        C0 = __builtin_amdgcn_mfma_f32_16x16x32_bf16(A02, B0, C0, 0, 0, 0);   \
        C1 = __builtin_amdgcn_mfma_f32_16x16x32_bf16(A10, B0, C1, 0, 0, 0);   \
        C1 = __builtin_amdgcn_mfma_f32_16x16x32_bf16(A10, B1, C1, 0, 0, 0);   \
        C1 = __builtin_amdgcn_mfma_f32_16x16x32_bf16(A11, B0, C1, 0, 0, 0);   \
        C1 = __builtin_amdgcn_mfma_f32_16x16x32_bf16(A11, B1, C1, 0, 0, 0);   \
        C1 = __builtin_amdgcn_mfma_f32_16x16x32_bf16(A10, B2, C1, 0, 0, 0);   \
        C1 = __builtin_amdgcn_mfma_f32_16x16x32_bf16(A12, B0, C1, 0, 0, 0);   \
    }                                                                         \
} while (0)

    for (int c = 0; c < NSQ; c += 2) {
        STEPBODY(c, pa00, pa01, pa10, pa11);
        STEPBODY(c + 1, pb00, pb01, pb10, pb11);
    }
#undef STEPBODY

    // ---- split-K combine: 4 barrier-phases over kh, fixed order (determ.) ----
    __syncthreads();
#pragma unroll
    for (int ph = 0; ph < 4; ++ph) {
        if (kh == ph) {
#pragma unroll
            for (int jj = 0; jj < 4; ++jj) {
                const int r0 = ((lane >> 4) << 2) + jj;         // rt0 row
                const int c0 = (2 * eh + 0) * 16 + (lane & 15);
                const int c1 = (2 * eh + 1) * 16 + (lane & 15);
                if (ph == 0) {
                    lg[r0 * 68 + c0] = acc00[jj];
                    lg[r0 * 68 + c1] = acc01[jj];
                    lg[(r0 + 16) * 68 + c0] = acc10[jj];
                    lg[(r0 + 16) * 68 + c1] = acc11[jj];
                } else {
                    lg[r0 * 68 + c0] += acc00[jj];
                    lg[r0 * 68 + c1] += acc01[jj];
                    lg[(r0 + 16) * 68 + c0] += acc10[jj];
                    lg[(r0 + 16) * 68 + c1] += acc11[jj];
                }
            }
        }
        __syncthreads();
    }

    // ---- per-row softmax stats + stable top-2 (one thread per row) ----
    float* rowm   = lg + BM * 68;
    float* rowinv = rowm + BM;
    if (tid < BM) {
        const int row = tid;
        float m = -3.4e38f;
        for (int e = 0; e < NE; ++e) m = fmaxf(m, lg[row * 68 + e]);
        float s = 0.f;
        float v1 = -1.f, v2 = -1.f;
        int   i1 = 0,    i2 = 0;
        for (int e = 0; e < NE; ++e) {
            const float p = __expf(lg[row * 68 + e] - m);
            s += p;
            if (p > v1)      { v2 = v1; i2 = i1; v1 = p; i1 = e; }
            else if (p > v2) { v2 = p; i2 = e; }
        }
        const float inv = 1.f / s;
        rowm[row]   = m;
        rowinv[row] = inv;
        const long grow = rowbase + row;
        const float p1 = v1 * inv, p2 = v2 * inv;
        const float dn = p1 + p2 + 1e-9f;
        out[NIDX + grow * 2 + 0] = (float)i1;
        out[NIDX + grow * 2 + 1] = (float)i2;
        out[NWTS + grow * 2 + 0] = p1 / dn;
        out[NWTS + grow * 2 + 1] = p2 / dn;
    }
    __syncthreads();

    // ---- probs write: 512 threads x 1 float4, coalesced ----
    {
        const int row = tid >> 4;
        const int e0  = (tid & 15) << 2;
        const float m = rowm[row], inv = rowinv[row];
        const long grow = rowbase + row;
        const float4 l4 = *reinterpret_cast<const float4*>(&lg[row * 68 + e0]);
        float4 p;
        p.x = __expf(l4.x - m) * inv;
        p.y = __expf(l4.y - m) * inv;
        p.z = __expf(l4.z - m) * inv;
        p.w = __expf(l4.w - m) * inv;
        *reinterpret_cast<float4*>(&out[grow * (long)NE + e0]) = p;
    }
}

extern "C" void kernel_launch(void* const* d_in, const int* in_sizes, int n_in,
                              void* d_out, int out_size, void* d_ws, size_t ws_size,
                              hipStream_t stream) {
    const float* x = (const float*)d_in[0];
    const float* W = (const float*)d_in[1];
    float* out = (float*)d_out;
    uint4* WF  = (uint4*)d_ws;   // 1.5 MB fragment-ordered W planes

    w_prep<<<dim3(128), dim3(256), 0, stream>>>(W, WF);
    token_router<<<dim3(BT / BM), dim3(512), 0, stream>>>(x, WF, out);
}